// Round 7
// baseline (1868.418 us; speedup 1.0000x reference)
//
#include <hip/hip_runtime.h>
#include <cstdint>
#include <cstddef>

#define TOK 2048
#define HID 2880
#define NI  2880
#define NG  5760
#define NE  8

typedef __attribute__((ext_vector_type(8))) short short8;
typedef __attribute__((ext_vector_type(4))) float f32x4;

// ---------- helpers ----------
__device__ __forceinline__ ushort f2bf(float f) {
  union { float f; uint32_t u; } v; v.f = f;
  uint32_t r = v.u + 0x7fffu + ((v.u >> 16) & 1u);   // RNE
  return (ushort)(r >> 16);
}

#define GLOAD_LDS16(g, l)                                                           \
  __builtin_amdgcn_global_load_lds(                                                 \
      (const __attribute__((address_space(1))) void*)(g),                           \
      (__attribute__((address_space(3))) void*)(l), 16, 0, 0)

// ---------- transpose + f32->bf16 convert ----------
// in : [NE][rows][cols] f32 ; out: [NE][cols(perm)][rows] bf16
// permHalf==0 : out_row = n.  permHalf==P : even n -> n/2, odd n -> P + n/2.
__global__ __launch_bounds__(256) void k_transpose(
    const float* __restrict__ in, ushort* __restrict__ out,
    int rows, int cols, int permHalf) {
  __shared__ float tile[64][65];
  const int e  = blockIdx.z;
  const int k0 = blockIdx.x * 64;
  const int n0 = blockIdx.y * 64;
  const size_t base = (size_t)e * rows * cols;
  const int t = threadIdx.x;
  const int r = t >> 2, q = t & 3;

  const float* src = in + base + (size_t)(k0 + r) * cols + n0;
#pragma unroll
  for (int j = 0; j < 4; ++j) {
    const int c = q * 4 + j * 16;
    const float4 v = *reinterpret_cast<const float4*>(src + c);
    tile[r][c + 0] = v.x; tile[r][c + 1] = v.y;
    tile[r][c + 2] = v.z; tile[r][c + 3] = v.w;
  }
  __syncthreads();

  const int n  = r;            // output source column
  const int ks = q * 16;       // 16 k's per thread
  const int ng = n0 + n;
  const int row_out = permHalf ? ((ng & 1) ? (permHalf + (ng >> 1)) : (ng >> 1)) : ng;

  uint32_t pk[8];
#pragma unroll
  for (int j = 0; j < 8; ++j) {
    const ushort lo = f2bf(tile[ks + 2 * j][n]);
    const ushort hi = f2bf(tile[ks + 2 * j + 1][n]);
    pk[j] = ((uint32_t)hi << 16) | lo;
  }
  uint4* dst = (uint4*)(out + base + (size_t)row_out * rows + k0 + ks);
  dst[0] = make_uint4(pk[0], pk[1], pk[2], pk[3]);
  dst[1] = make_uint4(pk[4], pk[5], pk[6], pk[7]);
}

// ---------- f32 -> bf16 row-major convert (hidden states) ----------
__global__ __launch_bounds__(256) void k_cvt_bf16(
    const float* __restrict__ in, ushort* __restrict__ out, int n8) {
  const int i = blockIdx.x * 256 + threadIdx.x;
  if (i < n8) {
    const float4 a = ((const float4*)in)[2 * i];
    const float4 b = ((const float4*)in)[2 * i + 1];
    uint4 o;
    o.x = ((uint32_t)f2bf(a.y) << 16) | f2bf(a.x);
    o.y = ((uint32_t)f2bf(a.w) << 16) | f2bf(a.z);
    o.z = ((uint32_t)f2bf(b.y) << 16) | f2bf(b.x);
    o.w = ((uint32_t)f2bf(b.w) << 16) | f2bf(b.z);
    ((uint4*)out)[i] = o;
  }
}

// ---------- GEMM1: gate_up + activation, writes rw-scaled gated bf16 ----------
// UNCHANGED from Round 5 (measured: 585 us, 928 TF = m97-structure ceiling,
// MfmaUtil 42.6%, bank-conflict 0).
__global__ __launch_bounds__(256, 3) void k_gemm1(
    const ushort* __restrict__ A, const ushort* __restrict__ Wt,
    const float* __restrict__ bias, const float* __restrict__ rw,
    ushort* __restrict__ gated) {
  // A[128][64] @0 | Bg[64][64] @8192 | Bu[64][64] @12288  (shorts, 32KB)
  __shared__ __align__(16) short lds[16384];
  const int tid  = threadIdx.x;
  const int lane = tid & 63;
  const int wid  = tid >> 6;
  const int wm   = wid >> 1;      // 0..1 : 64-row t slice
  const int wn   = wid & 1;       // 0..1 : 32-col slice of each of gate/up

  // T1 chunked swizzle (nwg=5760 -> bijective; 720 blocks/expert)
  const int bid = blockIdx.x;
  const int e   = bid & 7;         // one expert per XCD
  const int rr  = bid >> 3;        // 0..719
  const int i0  = (rr >> 4) * 64;  // 45 i-tiles
  const int t0  = (rr & 15) * 128; // 16 t-tiles (innermost)

  const ushort* WtE = Wt + (size_t)e * NG * HID;

  const f32x4 fz = {0.f, 0.f, 0.f, 0.f};
  f32x4 accg[4][2], accu[4][2];
#pragma unroll
  for (int a = 0; a < 4; ++a)
#pragma unroll
    for (int b = 0; b < 2; ++b) { accg[a][b] = fz; accu[a][b] = fz; }

  const int lr  = lane >> 3;               // staging: row within 8-row chunk
  const int ks  = ((lane & 7) ^ lr) * 8;   // staging: swizzled k-offset (shorts)
  const int fr  = lane & 15;               // fragment row/col
  const int fg  = lane >> 4;               // fragment k-group (0..3)
  const int fsw = lane & 7;                // read-side swizzle (= row&7)

  for (int kk = 0; kk < HID; kk += 64) {
    // stage 32KB: 32 chunks of 8 rows x 64k, 8 chunks per wave
#pragma unroll
    for (int c = wid; c < 32; c += 4) {
      const ushort* src;
      if (c < 16)      src = A   + (size_t)(t0 + c * 8 + lr) * HID + kk + ks;
      else if (c < 24) src = WtE + (size_t)(i0 + (c - 16) * 8 + lr) * HID + kk + ks;
      else             src = WtE + (size_t)(NI + i0 + (c - 24) * 8 + lr) * HID + kk + ks;
      GLOAD_LDS16(src, &lds[c * 512]);
    }
    __syncthreads();

#pragma unroll
    for (int half = 0; half < 2; ++half) {
      const int ko = ((half * 4 + fg) ^ fsw) * 8;   // swizzled chunk offset
      short8 af[4], bg[2], bu[2];
#pragma unroll
      for (int mi = 0; mi < 4; ++mi)
        af[mi] = *(const short8*)&lds[(wm * 64 + mi * 16 + fr) * 64 + ko];
#pragma unroll
      for (int ni = 0; ni < 2; ++ni) {
        bg[ni] = *(const short8*)&lds[8192  + (wn * 32 + ni * 16 + fr) * 64 + ko];
        bu[ni] = *(const short8*)&lds[12288 + (wn * 32 + ni * 16 + fr) * 64 + ko];
      }
#pragma unroll
      for (int mi = 0; mi < 4; ++mi)
#pragma unroll
        for (int ni = 0; ni < 2; ++ni) {
          accg[mi][ni] = __builtin_amdgcn_mfma_f32_16x16x32_bf16(af[mi], bg[ni], accg[mi][ni], 0, 0, 0);
          accu[mi][ni] = __builtin_amdgcn_mfma_f32_16x16x32_bf16(af[mi], bu[ni], accu[mi][ni], 0, 0, 0);
        }
    }
    __syncthreads();
  }

  // fused bias + clamp + glu + routing-weight epilogue
  float bg2[2], bu2[2];
  int iv[2];
#pragma unroll
  for (int ni = 0; ni < 2; ++ni) {
    iv[ni] = i0 + wn * 32 + ni * 16 + fr;
    bg2[ni] = bias[(size_t)e * NG + 2 * iv[ni]];
    bu2[ni] = bias[(size_t)e * NG + 2 * iv[ni] + 1];
  }
#pragma unroll
  for (int mi = 0; mi < 4; ++mi) {
#pragma unroll
    for (int j = 0; j < 4; ++j) {
      const int t = t0 + wm * 64 + mi * 16 + fg * 4 + j;
      const float rwv = rw[(size_t)t * NE + e];
#pragma unroll
      for (int ni = 0; ni < 2; ++ni) {
        float gate = accg[mi][ni][j] + bg2[ni];
        float up   = accu[mi][ni][j] + bu2[ni];
        gate = fminf(gate, 7.0f);
        up   = fminf(fmaxf(up, -7.0f), 7.0f);
        const float glu = gate / (1.0f + __expf(-1.702f * gate));
        gated[((size_t)e * TOK + t) * NI + iv[ni]] = f2bf(rwv * (up + 1.0f) * glu);
      }
    }
  }
}

// ---------- GEMM2: down proj, 2-way expert K-split, bigger wave-tile ----------
// Block 128t x 192h, waves 2x2 -> wave-tile 64x96 (acc 4x6): LDS-read/MFMA
// ratio 1.36 (was 1.9).  480 blocks = 2 splits x (15 h-tiles x 16 t-tiles).
// sid 0: experts 0-3 -> partial[0]; sid 1: experts 4-7 + sum_e rw*dbias ->
// partial[1].  XCD swizzle: XCDs 0-3 own split 0 (weights e0-3 L2-local).
// G: [NE][TOK][NI] bf16 (rw-scaled), Dt: [NE][HID][NI] bf16,
// rw: [TOK][NE] f32, dbias: [NE][HID] f32, partial: [2][TOK][HID] f32
__global__ __launch_bounds__(256, 3) void k_gemm2(
    const ushort* __restrict__ G, const ushort* __restrict__ Dt,
    const float* __restrict__ rw, const float* __restrict__ dbias,
    float* __restrict__ partial) {
  // A[128][64] @0 | B[192][64] @8192  (shorts, 40KB)
  __shared__ __align__(16) short lds[20480];
  const int tid  = threadIdx.x;
  const int lane = tid & 63;
  const int wid  = tid >> 6;
  const int wm   = wid >> 1;   // 0..1 : 64-row t slice
  const int wn   = wid & 1;    // 0..1 : 96-col h slice

  // T1 chunked swizzle (nwg=480 -> bijective; chunk=60/XCD)
  const int bid = blockIdx.x;
  const int swz = (bid & 7) * 60 + (bid >> 3);
  const int sid = (swz >= 240) ? 1 : 0;
  const int r   = swz - sid * 240;
  const int h0  = (r >> 4) * 192;   // 15 h-tiles
  const int t0  = (r & 15) * 128;   // 16 t-tiles (innermost)
  const int e0  = sid * 4;

  const f32x4 fz = {0.f, 0.f, 0.f, 0.f};
  f32x4 acc[4][6];
#pragma unroll
  for (int a = 0; a < 4; ++a)
#pragma unroll
    for (int b = 0; b < 6; ++b) acc[a][b] = fz;

  const int lr  = lane >> 3;               // staging row within 8-row chunk
  const int ks  = ((lane & 7) ^ lr) * 8;   // staging swizzled k-offset
  const int fr  = lane & 15;
  const int fg  = lane >> 4;
  const int fsw = lane & 7;

  for (int ee = 0; ee < 4; ++ee) {
    const ushort* Ge = G  + (size_t)(e0 + ee) * TOK * NI;
    const ushort* De = Dt + (size_t)(e0 + ee) * HID * NI;

    for (int kk = 0; kk < NI; kk += 64) {
      // stage 40KB: 40 chunks of 8 rows x 64k, 10 per wave
#pragma unroll
      for (int c = wid; c < 40; c += 4) {
        const ushort* src;
        if (c < 16) src = Ge + (size_t)(t0 + c * 8 + lr) * NI + kk + ks;
        else        src = De + (size_t)(h0 + (c - 16) * 8 + lr) * NI + kk + ks;
        GLOAD_LDS16(src, &lds[c * 512]);
      }
      __syncthreads();

#pragma unroll
      for (int half = 0; half < 2; ++half) {
        const int ko = ((half * 4 + fg) ^ fsw) * 8;
        short8 af[4], bf[6];
#pragma unroll
        for (int mi = 0; mi < 4; ++mi)
          af[mi] = *(const short8*)&lds[(wm * 64 + mi * 16 + fr) * 64 + ko];
#pragma unroll
        for (int ni = 0; ni < 6; ++ni)
          bf[ni] = *(const short8*)&lds[8192 + (wn * 96 + ni * 16 + fr) * 64 + ko];
#pragma unroll
        for (int mi = 0; mi < 4; ++mi)
#pragma unroll
          for (int ni = 0; ni < 6; ++ni)
            acc[mi][ni] = __builtin_amdgcn_mfma_f32_16x16x32_bf16(af[mi], bf[ni], acc[mi][ni], 0, 0, 0);
      }
      __syncthreads();
    }
  }

  // epilogue: split 0 writes raw partial; split 1 adds sum_e rw[t][e]*dbias[e][h]
  float* Pout = partial + (size_t)sid * TOK * HID;
  int hv[6];
#pragma unroll
  for (int ni = 0; ni < 6; ++ni) hv[ni] = h0 + wn * 96 + ni * 16 + fr;

  if (sid == 0) {
#pragma unroll
    for (int mi = 0; mi < 4; ++mi)
#pragma unroll
      for (int j = 0; j < 4; ++j) {
        const int t = t0 + wm * 64 + mi * 16 + fg * 4 + j;
#pragma unroll
        for (int ni = 0; ni < 6; ++ni)
          Pout[(size_t)t * HID + hv[ni]] = acc[mi][ni][j];
      }
  } else {
    float dbv[6][8];
#pragma unroll
    for (int ni = 0; ni < 6; ++ni)
#pragma unroll
      for (int e = 0; e < 8; ++e)
        dbv[ni][e] = dbias[(size_t)e * HID + hv[ni]];
#pragma unroll
    for (int mi = 0; mi < 4; ++mi)
#pragma unroll
      for (int j = 0; j < 4; ++j) {
        const int t = t0 + wm * 64 + mi * 16 + fg * 4 + j;
        const float4 r0 = *(const float4*)(rw + (size_t)t * NE);
        const float4 r1 = *(const float4*)(rw + (size_t)t * NE + 4);
#pragma unroll
        for (int ni = 0; ni < 6; ++ni) {
          float s = acc[mi][ni][j];
          s += r0.x * dbv[ni][0] + r0.y * dbv[ni][1] + r0.z * dbv[ni][2] + r0.w * dbv[ni][3];
          s += r1.x * dbv[ni][4] + r1.y * dbv[ni][5] + r1.z * dbv[ni][6] + r1.w * dbv[ni][7];
          Pout[(size_t)t * HID + hv[ni]] = s;
        }
      }
  }
}

// ---------- combine: out = partial[0] + partial[1] ----------
__global__ __launch_bounds__(256) void k_combine(
    const float* __restrict__ p, float* __restrict__ out, int n4) {
  const int i = blockIdx.x * 256 + threadIdx.x;
  if (i < n4) {
    const float4 a = ((const float4*)p)[i];
    const float4 b = ((const float4*)(p + (size_t)TOK * HID))[i];
    float4 o;
    o.x = a.x + b.x; o.y = a.y + b.y; o.z = a.z + b.z; o.w = a.w + b.w;
    ((float4*)out)[i] = o;
  }
}

// ---------- launch ----------
extern "C" void kernel_launch(void* const* d_in, const int* in_sizes, int n_in,
                              void* d_out, int out_size, void* d_ws, size_t ws_size,
                              hipStream_t stream) {
  const float* hs  = (const float*)d_in[0];   // [TOK][HID]
  const float* rw  = (const float*)d_in[1];   // [TOK][NE]
  const float* gup = (const float*)d_in[2];   // [NE][HID][NG]
  const float* gub = (const float*)d_in[3];   // [NE][NG]
  const float* dwn = (const float*)d_in[4];   // [NE][NI][HID]
  const float* dnb = (const float*)d_in[5];   // [NE][HID]
  float* out = (float*)d_out;

  char* ws = (char*)d_ws;
  // ws layout (bytes):
  //   gupT : [NE][NG][HID] bf16   = 265,420,800   (dead after k_gemm1 ->
  //                                  reused as partial[2][TOK][HID] f32 = 47.2MB)
  //   downT: [NE][HID][NI] bf16   = 132,710,400
  //   hidB : [TOK][HID] bf16      =  11,796,480
  //   gated: [NE][TOK][NI] bf16   =  94,371,840   (total ~504.3 MB)
  ushort* gupT  = (ushort*)(ws);
  ushort* downT = (ushort*)(ws + 265420800u);
  ushort* hidB  = (ushort*)(ws + 265420800u + 132710400u);
  ushort* gated = (ushort*)(ws + 265420800u + 132710400u + 11796480u);
  float*  part  = (float*)(ws);               // overlays gupT (dead by then)

  // 1) weight transposes (+bf16 convert, +gate/up de-interleave)
  k_transpose<<<dim3(HID / 64, NG / 64, NE), 256, 0, stream>>>(gup, gupT, HID, NG, NI);
  k_transpose<<<dim3(NI / 64, HID / 64, NE), 256, 0, stream>>>(dwn, downT, NI, HID, 0);
  // 2) hidden -> bf16
  k_cvt_bf16<<<(TOK * HID / 8 + 255) / 256, 256, 0, stream>>>(hs, hidB, TOK * HID / 8);
  // 3) gate_up GEMM + fused activation + routing-weight scaling (XCD-swizzled)
  k_gemm1<<<5760, 256, 0, stream>>>(hidB, gupT, gub, rw, gated);
  // 4) down GEMM, 2-way expert K-split (XCD-swizzled), partials into ws
  k_gemm2<<<480, 256, 0, stream>>>(gated, downT, rw, dnb, part);
  // 5) combine partials
  k_combine<<<(TOK * HID / 4) / 256, 256, 0, stream>>>(part, out, TOK * HID / 4);
}

// Round 10
// 1834.881 us; speedup vs baseline: 1.0183x; 1.0183x over previous
//
#include <hip/hip_runtime.h>
#include <cstdint>
#include <cstddef>

#define TOK 2048
#define HID 2880
#define NI  2880
#define NG  5760
#define NE  8

typedef __attribute__((ext_vector_type(8))) short short8;
typedef __attribute__((ext_vector_type(4))) float f32x4;

// ---------- helpers ----------
__device__ __forceinline__ ushort f2bf(float f) {
  union { float f; uint32_t u; } v; v.f = f;
  uint32_t r = v.u + 0x7fffu + ((v.u >> 16) & 1u);   // RNE
  return (ushort)(r >> 16);
}

#define GLOAD_LDS16(g, l)                                                           \
  __builtin_amdgcn_global_load_lds(                                                 \
      (const __attribute__((address_space(1))) void*)(g),                           \
      (__attribute__((address_space(3))) void*)(l), 16, 0, 0)

// ---------- transpose + f32->bf16 convert ----------
// in : [NE][rows][cols] f32 ; out: [NE][cols(perm)][rows] bf16
// permHalf==0 : out_row = n.  permHalf==P : even n -> n/2, odd n -> P + n/2.
__global__ __launch_bounds__(256) void k_transpose(
    const float* __restrict__ in, ushort* __restrict__ out,
    int rows, int cols, int permHalf) {
  __shared__ float tile[64][65];
  const int e  = blockIdx.z;
  const int k0 = blockIdx.x * 64;
  const int n0 = blockIdx.y * 64;
  const size_t base = (size_t)e * rows * cols;
  const int t = threadIdx.x;
  const int r = t >> 2, q = t & 3;

  const float* src = in + base + (size_t)(k0 + r) * cols + n0;
#pragma unroll
  for (int j = 0; j < 4; ++j) {
    const int c = q * 4 + j * 16;
    const float4 v = *reinterpret_cast<const float4*>(src + c);
    tile[r][c + 0] = v.x; tile[r][c + 1] = v.y;
    tile[r][c + 2] = v.z; tile[r][c + 3] = v.w;
  }
  __syncthreads();

  const int n  = r;            // output source column
  const int ks = q * 16;       // 16 k's per thread
  const int ng = n0 + n;
  const int row_out = permHalf ? ((ng & 1) ? (permHalf + (ng >> 1)) : (ng >> 1)) : ng;

  uint32_t pk[8];
#pragma unroll
  for (int j = 0; j < 8; ++j) {
    const ushort lo = f2bf(tile[ks + 2 * j][n]);
    const ushort hi = f2bf(tile[ks + 2 * j + 1][n]);
    pk[j] = ((uint32_t)hi << 16) | lo;
  }
  uint4* dst = (uint4*)(out + base + (size_t)row_out * rows + k0 + ks);
  dst[0] = make_uint4(pk[0], pk[1], pk[2], pk[3]);
  dst[1] = make_uint4(pk[4], pk[5], pk[6], pk[7]);
}

// ---------- f32 -> bf16 row-major convert (hidden states) ----------
__global__ __launch_bounds__(256) void k_cvt_bf16(
    const float* __restrict__ in, ushort* __restrict__ out, int n8) {
  const int i = blockIdx.x * 256 + threadIdx.x;
  if (i < n8) {
    const float4 a = ((const float4*)in)[2 * i];
    const float4 b = ((const float4*)in)[2 * i + 1];
    uint4 o;
    o.x = ((uint32_t)f2bf(a.y) << 16) | f2bf(a.x);
    o.y = ((uint32_t)f2bf(a.w) << 16) | f2bf(a.z);
    o.z = ((uint32_t)f2bf(b.y) << 16) | f2bf(b.x);
    o.w = ((uint32_t)f2bf(b.w) << 16) | f2bf(b.z);
    ((uint4*)out)[i] = o;
  }
}

// ---------- GEMM1: gate_up + activation, writes rw-scaled gated bf16 ----------
// Round-5 structure (measured 585-590 us, 928 TF, MfmaUtil 43, bank-conf 0).
// Round-7 experiment (STILL UNMEASURED): __launch_bounds__(256,4) — 68 VGPR +
// 64 AGPR = 132 combined capped occupancy at 3 waves/SIMD (measured 33%);
// forcing 128 combined gives 4 blocks/CU (LDS 4x32KB=128KB <= 160KB).
// Falsifier: if g1 >= 620us with spill (scratch traffic), revert to (256,3).
__global__ __launch_bounds__(256, 4) void k_gemm1(
    const ushort* __restrict__ A, const ushort* __restrict__ Wt,
    const float* __restrict__ bias, const float* __restrict__ rw,
    ushort* __restrict__ gated) {
  // A[128][64] @0 | Bg[64][64] @8192 | Bu[64][64] @12288  (shorts, 32KB)
  __shared__ __align__(16) short lds[16384];
  const int tid  = threadIdx.x;
  const int lane = tid & 63;
  const int wid  = tid >> 6;
  const int wm   = wid >> 1;      // 0..1 : 64-row t slice
  const int wn   = wid & 1;       // 0..1 : 32-col slice of each of gate/up

  // T1 chunked swizzle (nwg=5760 -> bijective; 720 blocks/expert)
  const int bid = blockIdx.x;
  const int e   = bid & 7;         // one expert per XCD
  const int rr  = bid >> 3;        // 0..719
  const int i0  = (rr >> 4) * 64;  // 45 i-tiles
  const int t0  = (rr & 15) * 128; // 16 t-tiles (innermost)

  const ushort* WtE = Wt + (size_t)e * NG * HID;

  const f32x4 fz = {0.f, 0.f, 0.f, 0.f};
  f32x4 accg[4][2], accu[4][2];
#pragma unroll
  for (int a = 0; a < 4; ++a)
#pragma unroll
    for (int b = 0; b < 2; ++b) { accg[a][b] = fz; accu[a][b] = fz; }

  const int lr  = lane >> 3;               // staging: row within 8-row chunk
  const int ks  = ((lane & 7) ^ lr) * 8;   // staging: swizzled k-offset (shorts)
  const int fr  = lane & 15;               // fragment row/col
  const int fg  = lane >> 4;               // fragment k-group (0..3)
  const int fsw = lane & 7;                // read-side swizzle (= row&7)

  for (int kk = 0; kk < HID; kk += 64) {
    // stage 32KB: 32 chunks of 8 rows x 64k, 8 chunks per wave
#pragma unroll
    for (int c = wid; c < 32; c += 4) {
      const ushort* src;
      if (c < 16)      src = A   + (size_t)(t0 + c * 8 + lr) * HID + kk + ks;
      else if (c < 24) src = WtE + (size_t)(i0 + (c - 16) * 8 + lr) * HID + kk + ks;
      else             src = WtE + (size_t)(NI + i0 + (c - 24) * 8 + lr) * HID + kk + ks;
      GLOAD_LDS16(src, &lds[c * 512]);
    }
    __syncthreads();

#pragma unroll
    for (int half = 0; half < 2; ++half) {
      const int ko = ((half * 4 + fg) ^ fsw) * 8;   // swizzled chunk offset
      short8 af[4], bg[2], bu[2];
#pragma unroll
      for (int mi = 0; mi < 4; ++mi)
        af[mi] = *(const short8*)&lds[(wm * 64 + mi * 16 + fr) * 64 + ko];
#pragma unroll
      for (int ni = 0; ni < 2; ++ni) {
        bg[ni] = *(const short8*)&lds[8192  + (wn * 32 + ni * 16 + fr) * 64 + ko];
        bu[ni] = *(const short8*)&lds[12288 + (wn * 32 + ni * 16 + fr) * 64 + ko];
      }
#pragma unroll
      for (int mi = 0; mi < 4; ++mi)
#pragma unroll
        for (int ni = 0; ni < 2; ++ni) {
          accg[mi][ni] = __builtin_amdgcn_mfma_f32_16x16x32_bf16(af[mi], bg[ni], accg[mi][ni], 0, 0, 0);
          accu[mi][ni] = __builtin_amdgcn_mfma_f32_16x16x32_bf16(af[mi], bu[ni], accu[mi][ni], 0, 0, 0);
        }
    }
    __syncthreads();
  }

  // fused bias + clamp + glu + routing-weight epilogue
  float bg2[2], bu2[2];
  int iv[2];
#pragma unroll
  for (int ni = 0; ni < 2; ++ni) {
    iv[ni] = i0 + wn * 32 + ni * 16 + fr;
    bg2[ni] = bias[(size_t)e * NG + 2 * iv[ni]];
    bu2[ni] = bias[(size_t)e * NG + 2 * iv[ni] + 1];
  }
#pragma unroll
  for (int mi = 0; mi < 4; ++mi) {
#pragma unroll
    for (int j = 0; j < 4; ++j) {
      const int t = t0 + wm * 64 + mi * 16 + fg * 4 + j;
      const float rwv = rw[(size_t)t * NE + e];
#pragma unroll
      for (int ni = 0; ni < 2; ++ni) {
        float gate = accg[mi][ni][j] + bg2[ni];
        float up   = accu[mi][ni][j] + bu2[ni];
        gate = fminf(gate, 7.0f);
        up   = fminf(fmaxf(up, -7.0f), 7.0f);
        const float glu = gate / (1.0f + __expf(-1.702f * gate));
        gated[((size_t)e * TOK + t) * NI + iv[ni]] = f2bf(rwv * (up + 1.0f) * glu);
      }
    }
  }
}

// ---------- GEMM2: down proj, flat accumulation over experts ----------
// Round-6 structure (128x96 tile, no split) with __launch_bounds__(256,4):
// 48 AGPR + ~60 VGPR = ~108 combined <= 128 -> 4 blocks/CU (LDS 4x28=112KB).
// G: [NE][TOK][NI] bf16 (rw-scaled), Dt: [NE][HID][NI] bf16,
// rw: [TOK][NE] f32, dbias: [NE][HID] f32, out: [TOK][HID] f32
__global__ __launch_bounds__(256, 4) void k_gemm2(
    const ushort* __restrict__ G, const ushort* __restrict__ Dt,
    const float* __restrict__ rw, const float* __restrict__ dbias,
    float* __restrict__ out) {
  // A[128][64] @0 | B[96][64] @8192  (shorts, 28KB)
  __shared__ __align__(16) short lds[14336];
  const int tid  = threadIdx.x;
  const int lane = tid & 63;
  const int wid  = tid >> 6;
  const int wm   = wid >> 1;
  const int wn   = wid & 1;

  // T1 chunked swizzle (nwg=480 -> bijective; chunk=60)
  const int bid = blockIdx.x;
  const int swz = (bid & 7) * 60 + (bid >> 3);
  const int h0  = (swz >> 4) * 96;   // 30 h-tiles
  const int t0  = (swz & 15) * 128;  // 16 t-tiles (innermost)

  const f32x4 fz = {0.f, 0.f, 0.f, 0.f};
  f32x4 acc[4][3];
#pragma unroll
  for (int a = 0; a < 4; ++a)
#pragma unroll
    for (int b = 0; b < 3; ++b) acc[a][b] = fz;

  const int lr  = lane >> 3;
  const int ks  = ((lane & 7) ^ lr) * 8;
  const int fr  = lane & 15;
  const int fg  = lane >> 4;
  const int fsw = lane & 7;

  for (int e = 0; e < NE; ++e) {
    const ushort* Ge = G  + (size_t)e * TOK * NI;
    const ushort* De = Dt + (size_t)e * HID * NI;

    for (int kk = 0; kk < NI; kk += 64) {
      // stage 28KB: 28 chunks of 8 rows x 64k, 7 per wave
#pragma unroll
      for (int c = wid; c < 28; c += 4) {
        const ushort* src;
        if (c < 16) src = Ge + (size_t)(t0 + c * 8 + lr) * NI + kk + ks;
        else        src = De + (size_t)(h0 + (c - 16) * 8 + lr) * NI + kk + ks;
        GLOAD_LDS16(src, &lds[c * 512]);
      }
      __syncthreads();

#pragma unroll
      for (int half = 0; half < 2; ++half) {
        const int ko = ((half * 4 + fg) ^ fsw) * 8;
        short8 af[4], bf[3];
#pragma unroll
        for (int mi = 0; mi < 4; ++mi)
          af[mi] = *(const short8*)&lds[(wm * 64 + mi * 16 + fr) * 64 + ko];
#pragma unroll
        for (int ni = 0; ni < 3; ++ni)
          bf[ni] = *(const short8*)&lds[8192 + (wn * 48 + ni * 16 + fr) * 64 + ko];
#pragma unroll
        for (int mi = 0; mi < 4; ++mi)
#pragma unroll
          for (int ni = 0; ni < 3; ++ni)
            acc[mi][ni] = __builtin_amdgcn_mfma_f32_16x16x32_bf16(af[mi], bf[ni], acc[mi][ni], 0, 0, 0);
      }
      __syncthreads();
    }
  }

  // epilogue: out = acc + sum_e rw[t][e] * dbias[e][h]
  int hv[3];
  float dbv[3][8];
#pragma unroll
  for (int ni = 0; ni < 3; ++ni) {
    hv[ni] = h0 + wn * 48 + ni * 16 + fr;
#pragma unroll
    for (int e = 0; e < 8; ++e)
      dbv[ni][e] = dbias[(size_t)e * HID + hv[ni]];
  }
#pragma unroll
  for (int mi = 0; mi < 4; ++mi) {
#pragma unroll
    for (int j = 0; j < 4; ++j) {
      const int t = t0 + wm * 64 + mi * 16 + fg * 4 + j;
      const float4 r0 = *(const float4*)(rw + (size_t)t * NE);
      const float4 r1 = *(const float4*)(rw + (size_t)t * NE + 4);
#pragma unroll
      for (int ni = 0; ni < 3; ++ni) {
        float s = acc[mi][ni][j];
        s += r0.x * dbv[ni][0] + r0.y * dbv[ni][1] + r0.z * dbv[ni][2] + r0.w * dbv[ni][3];
        s += r1.x * dbv[ni][4] + r1.y * dbv[ni][5] + r1.z * dbv[ni][6] + r1.w * dbv[ni][7];
        out[(size_t)t * HID + hv[ni]] = s;
      }
    }
  }
}

// ---------- launch ----------
extern "C" void kernel_launch(void* const* d_in, const int* in_sizes, int n_in,
                              void* d_out, int out_size, void* d_ws, size_t ws_size,
                              hipStream_t stream) {
  const float* hs  = (const float*)d_in[0];   // [TOK][HID]
  const float* rw  = (const float*)d_in[1];   // [TOK][NE]
  const float* gup = (const float*)d_in[2];   // [NE][HID][NG]
  const float* gub = (const float*)d_in[3];   // [NE][NG]
  const float* dwn = (const float*)d_in[4];   // [NE][NI][HID]
  const float* dnb = (const float*)d_in[5];   // [NE][HID]
  float* out = (float*)d_out;

  char* ws = (char*)d_ws;
  // ws layout (bytes):
  //   gupT : [NE][NG][HID] bf16   = 265,420,800
  //   downT: [NE][HID][NI] bf16   = 132,710,400
  //   hidB : [TOK][HID] bf16      =  11,796,480
  //   gated: [NE][TOK][NI] bf16   =  94,371,840   (total ~504.3 MB)
  ushort* gupT  = (ushort*)(ws);
  ushort* downT = (ushort*)(ws + 265420800u);
  ushort* hidB  = (ushort*)(ws + 265420800u + 132710400u);
  ushort* gated = (ushort*)(ws + 265420800u + 132710400u + 11796480u);

  // 1) weight transposes (+bf16 convert, +gate/up de-interleave)
  k_transpose<<<dim3(HID / 64, NG / 64, NE), 256, 0, stream>>>(gup, gupT, HID, NG, NI);
  k_transpose<<<dim3(NI / 64, HID / 64, NE), 256, 0, stream>>>(dwn, downT, NI, HID, 0);
  // 2) hidden -> bf16
  k_cvt_bf16<<<(TOK * HID / 8 + 255) / 256, 256, 0, stream>>>(hs, hidB, TOK * HID / 8);
  // 3) gate_up GEMM + fused activation + routing-weight scaling (XCD-swizzled)
  k_gemm1<<<5760, 256, 0, stream>>>(hidB, gupT, gub, rw, gated);
  // 4) down GEMM, flat accumulation over all experts (XCD-swizzled)
  k_gemm2<<<480, 256, 0, stream>>>(gated, downT, rw, dnb, out);
}